// Round 1
// baseline (264.743 us; speedup 1.0000x reference)
//
#include <hip/hip_runtime.h>
#include <hip/hip_bf16.h>

#define D 384
#define NROWS 16384
#define BATCH 4
#define MG 512
#define RTOT (BATCH * NROWS) /* 65536 */
#define NC (2 * D)           /* 768 combined output cols: [g | f] */

typedef __attribute__((ext_vector_type(8))) short bf16x8;
typedef __attribute__((ext_vector_type(4))) float f32x4;

static __device__ __forceinline__ unsigned short f2bf(float f) {
  unsigned int u = __float_as_uint(f);
  unsigned int r = u + 0x7fffu + ((u >> 16) & 1u); // RNE
  return (unsigned short)(r >> 16);
}
static __device__ __forceinline__ float bf2f(unsigned short h) {
  return __uint_as_float(((unsigned int)h) << 16);
}

// ---------------- conversions ----------------
__global__ void k_convert_x(const float* __restrict__ x, unsigned short* __restrict__ xb) {
  const long total4 = (long)RTOT * D / 4;
  for (long i = blockIdx.x * (long)blockDim.x + threadIdx.x; i < total4;
       i += (long)gridDim.x * blockDim.x) {
    float4 v = ((const float4*)x)[i];
    ushort4 o;
    o.x = f2bf(v.x); o.y = f2bf(v.y); o.z = f2bf(v.z); o.w = f2bf(v.w);
    ((ushort4*)xb)[i] = o;
  }
}

__global__ void k_build_w(const float* __restrict__ g_w, const float* __restrict__ f_w,
                          const float* __restrict__ h_w,
                          unsigned short* __restrict__ wt, unsigned short* __restrict__ hw) {
  const int totW = NC * D, totH = D * D;
  int tid0 = blockIdx.x * blockDim.x + threadIdx.x;
  int stride = gridDim.x * blockDim.x;
  for (int idx = tid0; idx < totW; idx += stride) {
    int c = idx / D, k = idx % D;
    float v = (c < D) ? g_w[c * D + k] : f_w[(c - D) * D + k];
    wt[idx] = f2bf(v);
  }
  for (int idx = tid0; idx < totH; idx += stride) hw[idx] = f2bf(h_w[idx]);
}

// ---------------- CSR build (one block) ----------------
__global__ void k_csr(const int* __restrict__ ii, int* __restrict__ csr_start,
                      int* __restrict__ csr_rows) {
  __shared__ int cnt[MG];
  int t = threadIdx.x; // 512 threads
  cnt[t] = 0;
  __syncthreads();
  for (int n = t; n < NROWS; n += MG) atomicAdd(&cnt[ii[n]], 1);
  __syncthreads();
  if (t == 0) {
    int run = 0;
    for (int i = 0; i < MG; i++) {
      int c = cnt[i];
      cnt[i] = run;
      csr_start[i] = run;
      run += c;
    }
    csr_start[MG] = run;
  }
  __syncthreads();
  for (int n = t; n < NROWS; n += MG) {
    int pos = atomicAdd(&cnt[ii[n]], 1);
    csr_rows[pos] = n;
  }
}

// ---------------- big GEMM: C = x @ [g_w;f_w]^T, epilogue exp/bias ----------------
#define BM 128
#define BNB 128
#define BK 32
__global__ __launch_bounds__(256) void k_gemm1(
    const unsigned short* __restrict__ xb, const unsigned short* __restrict__ wt,
    const float* __restrict__ g_b, const float* __restrict__ f_b,
    unsigned short* __restrict__ E, unsigned short* __restrict__ FXB) {
  __shared__ __attribute__((aligned(16))) unsigned short As[BM * BK];
  __shared__ __attribute__((aligned(16))) unsigned short Bs[BNB * BK];
  const int tid = threadIdx.x;
  const int lane = tid & 63, wid = tid >> 6;
  const int wr = wid >> 1, wc = wid & 1;
  const int row0 = blockIdx.y * BM, col0 = blockIdx.x * BNB;
  const char* aBase = (const char*)xb + (size_t)row0 * (D * 2);
  const char* bBase = (const char*)wt + (size_t)col0 * (D * 2);

  f32x4 acc[4][4];
#pragma unroll
  for (int m = 0; m < 4; m++)
#pragma unroll
    for (int n = 0; n < 4; n++) acc[m][n] = (f32x4){0.f, 0.f, 0.f, 0.f};

  const int o1 = tid * 16;        // bytes 0..4095   (rows 0..63 of tile)
  const int o2 = 4096 + tid * 16; // bytes 4096..8191 (rows 64..127)

  for (int kt = 0; kt < D / BK; kt++) {
    const int kb = kt * (BK * 2); // byte offset along K
    int4 a1 = *(const int4*)(aBase + (size_t)(o1 / 64) * (D * 2) + kb + (o1 % 64));
    int4 a2 = *(const int4*)(aBase + (size_t)(o2 / 64) * (D * 2) + kb + (o2 % 64));
    int4 b1 = *(const int4*)(bBase + (size_t)(o1 / 64) * (D * 2) + kb + (o1 % 64));
    int4 b2 = *(const int4*)(bBase + (size_t)(o2 / 64) * (D * 2) + kb + (o2 % 64));
    __syncthreads();
    *(int4*)((char*)As + o1) = a1;
    *(int4*)((char*)As + o2) = a2;
    *(int4*)((char*)Bs + o1) = b1;
    *(int4*)((char*)Bs + o2) = b2;
    __syncthreads();

    bf16x8 af[4], bfr[4];
#pragma unroll
    for (int m = 0; m < 4; m++)
      af[m] = *(const bf16x8*)(As + (wr * 64 + m * 16 + (lane & 15)) * BK + (lane >> 4) * 8);
#pragma unroll
    for (int n = 0; n < 4; n++)
      bfr[n] = *(const bf16x8*)(Bs + (wc * 64 + n * 16 + (lane & 15)) * BK + (lane >> 4) * 8);
#pragma unroll
    for (int m = 0; m < 4; m++)
#pragma unroll
      for (int n = 0; n < 4; n++)
        acc[m][n] = __builtin_amdgcn_mfma_f32_16x16x32_bf16(af[m], bfr[n], acc[m][n], 0, 0, 0);
  }

  const bool isG = (col0 < D); // block-uniform: cols [0,384) -> E, [384,768) -> FXB
#pragma unroll
  for (int m = 0; m < 4; m++) {
    const int grow0 = row0 + wr * 64 + m * 16 + ((lane >> 4) * 4);
#pragma unroll
    for (int n = 0; n < 4; n++) {
      const int gcol = col0 + wc * 64 + n * 16 + (lane & 15);
#pragma unroll
      for (int r = 0; r < 4; r++) {
        const int grow = grow0 + r;
        const float v = acc[m][n][r];
        if (isG) {
          E[(size_t)grow * D + gcol] = f2bf(expf(v + g_b[gcol]));
        } else {
          FXB[(size_t)grow * D + (gcol - D)] = f2bf(v + f_b[gcol - D]);
        }
      }
    }
  }
}

// ---------------- segment sums + divide ----------------
__global__ __launch_bounds__(384) void k_seg(
    const unsigned short* __restrict__ E, const unsigned short* __restrict__ FXB,
    const int* __restrict__ csr_start, const int* __restrict__ csr_rows,
    unsigned short* __restrict__ ypre) {
  const int m = blockIdx.x, b = blockIdx.y, d = threadIdx.x;
  const int s = csr_start[m], e = csr_start[m + 1];
  float s1 = 0.f, s2 = 0.f;
  for (int i = s; i < e; i++) {
    const int n = csr_rows[i];
    const size_t off = ((size_t)(b * NROWS + n)) * D + d;
    const float ev = bf2f(E[off]);
    const float fv = bf2f(FXB[off]);
    s1 += ev;
    s2 += fv * ev;
  }
  const float y = s2 / (s1 + 1e-6f);
  ypre[((size_t)(b * MG + m)) * D + d] = f2bf(y);
}

// ---------------- small GEMM: Outpre = Ypre @ h_w^T + h_b ----------------
__global__ __launch_bounds__(256) void k_gemm2(
    const unsigned short* __restrict__ ypre, const unsigned short* __restrict__ hw,
    const float* __restrict__ h_b, float* __restrict__ outpre) {
  const int tid = threadIdx.x, lane = tid & 63, wid = tid >> 6;
  const int r0 = blockIdx.y * 16;
  const int c0 = blockIdx.x * 64 + wid * 16;
  f32x4 acc = (f32x4){0.f, 0.f, 0.f, 0.f};
  const unsigned short* aRow = ypre + (size_t)(r0 + (lane & 15)) * D + (lane >> 4) * 8;
  const unsigned short* bRow = hw + (size_t)(c0 + (lane & 15)) * D + (lane >> 4) * 8;
#pragma unroll
  for (int kt = 0; kt < D / 32; kt++) {
    bf16x8 af = *(const bf16x8*)(aRow + kt * 32);
    bf16x8 bf_ = *(const bf16x8*)(bRow + kt * 32);
    acc = __builtin_amdgcn_mfma_f32_16x16x32_bf16(af, bf_, acc, 0, 0, 0);
  }
  const int col = c0 + (lane & 15);
  const float hb = h_b[col];
#pragma unroll
  for (int r = 0; r < 4; r++) {
    const int row = r0 + (lane >> 4) * 4 + r;
    outpre[(size_t)row * D + col] = acc[r] + hb;
  }
}

// ---------------- gather rows ----------------
__global__ void k_gather(const float* __restrict__ outpre, const int* __restrict__ ii,
                         float* __restrict__ out) {
  const long total4 = (long)RTOT * (D / 4); // 96 float4 per row
  for (long i = blockIdx.x * (long)blockDim.x + threadIdx.x; i < total4;
       i += (long)gridDim.x * blockDim.x) {
    const long row = i / (D / 4);
    const int q = (int)(i % (D / 4));
    const int b = (int)(row >> 14);
    const int n = (int)(row & (NROWS - 1));
    const int g = ii[n];
    ((float4*)out)[i] = ((const float4*)outpre)[((size_t)(b * MG + g)) * (D / 4) + q];
  }
}

extern "C" void kernel_launch(void* const* d_in, const int* in_sizes, int n_in,
                              void* d_out, int out_size, void* d_ws, size_t ws_size,
                              hipStream_t stream) {
  const float* x = (const float*)d_in[0];
  const int* ii = (const int*)d_in[1];
  const float* f_w = (const float*)d_in[2];
  const float* f_b = (const float*)d_in[3];
  const float* g_w = (const float*)d_in[4];
  const float* g_b = (const float*)d_in[5];
  const float* h_w = (const float*)d_in[6];
  const float* h_b = (const float*)d_in[7];
  float* out = (float*)d_out;

  char* ws = (char*)d_ws;
  size_t off = 0;
  auto alloc = [&](size_t bytes) {
    size_t p = off;
    off = (off + bytes + 255) & ~(size_t)255;
    return p;
  };
  unsigned short* xb = (unsigned short*)(ws + alloc((size_t)RTOT * D * 2));
  unsigned short* wt = (unsigned short*)(ws + alloc((size_t)NC * D * 2));
  unsigned short* hw = (unsigned short*)(ws + alloc((size_t)D * D * 2));
  unsigned short* E = (unsigned short*)(ws + alloc((size_t)RTOT * D * 2));
  unsigned short* FXB = (unsigned short*)(ws + alloc((size_t)RTOT * D * 2));
  unsigned short* ypre = (unsigned short*)(ws + alloc((size_t)BATCH * MG * D * 2));
  float* outpre = (float*)(ws + alloc((size_t)BATCH * MG * D * 4));
  int* csr_start = (int*)(ws + alloc((MG + 1) * 4));
  int* csr_rows = (int*)(ws + alloc((size_t)NROWS * 4));

  k_convert_x<<<dim3(4096), dim3(256), 0, stream>>>(x, xb);
  k_build_w<<<dim3(1152), dim3(256), 0, stream>>>(g_w, f_w, h_w, wt, hw);
  k_csr<<<dim3(1), dim3(MG), 0, stream>>>(ii, csr_start, csr_rows);
  k_gemm1<<<dim3(NC / BNB, RTOT / BM), dim3(256), 0, stream>>>(xb, wt, g_b, f_b, E, FXB);
  k_seg<<<dim3(MG, BATCH), dim3(D), 0, stream>>>(E, FXB, csr_start, csr_rows, ypre);
  k_gemm2<<<dim3(D / 64, (BATCH * MG) / 16), dim3(256), 0, stream>>>(ypre, hw, h_b, outpre);
  k_gather<<<dim3(4096), dim3(256), 0, stream>>>(outpre, ii, out);
}

// Round 2
// 197.552 us; speedup vs baseline: 1.3401x; 1.3401x over previous
//
#include <hip/hip_runtime.h>
#include <hip/hip_bf16.h>

#define D 384
#define NROWS 16384
#define BATCH 4
#define MG 512
#define RTOT (BATCH * NROWS) /* 65536 */
#define NC (2 * D)           /* 768 combined output cols: [g | f] */

typedef __attribute__((ext_vector_type(8))) short bf16x8;
typedef __attribute__((ext_vector_type(4))) float f32x4;

static __device__ __forceinline__ unsigned short f2bf(float f) {
  unsigned int u = __float_as_uint(f);
  unsigned int r = u + 0x7fffu + ((u >> 16) & 1u); // RNE
  return (unsigned short)(r >> 16);
}
static __device__ __forceinline__ float bf2f(unsigned short h) {
  return __uint_as_float(((unsigned int)h) << 16);
}

typedef __attribute__((address_space(1))) const void gvoid_t;
typedef __attribute__((address_space(3))) void lvoid_t;
static __device__ __forceinline__ void gl16(const void* g, void* l) {
  __builtin_amdgcn_global_load_lds((gvoid_t*)g, (lvoid_t*)l, 16, 0, 0);
}

// ---------------- conversions ----------------
__global__ void k_convert_x(const float* __restrict__ x, unsigned short* __restrict__ xb) {
  const long total4 = (long)RTOT * D / 4;
  for (long i = blockIdx.x * (long)blockDim.x + threadIdx.x; i < total4;
       i += (long)gridDim.x * blockDim.x) {
    float4 v = ((const float4*)x)[i];
    ushort4 o;
    o.x = f2bf(v.x); o.y = f2bf(v.y); o.z = f2bf(v.z); o.w = f2bf(v.w);
    ((ushort4*)xb)[i] = o;
  }
}

__global__ void k_build_w(const float* __restrict__ g_w, const float* __restrict__ f_w,
                          const float* __restrict__ h_w,
                          unsigned short* __restrict__ wt, unsigned short* __restrict__ hw) {
  const int totW = NC * D, totH = D * D;
  int tid0 = blockIdx.x * blockDim.x + threadIdx.x;
  int stride = gridDim.x * blockDim.x;
  for (int idx = tid0; idx < totW; idx += stride) {
    int c = idx / D, k = idx % D;
    float v = (c < D) ? g_w[c * D + k] : f_w[(c - D) * D + k];
    wt[idx] = f2bf(v);
  }
  for (int idx = tid0; idx < totH; idx += stride) hw[idx] = f2bf(h_w[idx]);
}

// ---------------- CSR build (one block) ----------------
__global__ void k_csr(const int* __restrict__ ii, int* __restrict__ csr_start,
                      int* __restrict__ csr_rows) {
  __shared__ int cnt[MG];
  int t = threadIdx.x; // 512 threads
  cnt[t] = 0;
  __syncthreads();
  for (int n = t; n < NROWS; n += MG) atomicAdd(&cnt[ii[n]], 1);
  __syncthreads();
  if (t == 0) {
    int run = 0;
    for (int i = 0; i < MG; i++) {
      int c = cnt[i];
      cnt[i] = run;
      csr_start[i] = run;
      run += c;
    }
    csr_start[MG] = run;
  }
  __syncthreads();
  for (int n = t; n < NROWS; n += MG) {
    int pos = atomicAdd(&cnt[ii[n]], 1);
    csr_rows[pos] = n;
  }
}

// ---------------- big GEMM: C = x @ [g_w;f_w]^T, epilogue exp/bias ----------------
// m97 structure: global_load_lds(16B) staging, 2-barrier loop, 128x128 tile.
// XCD swizzle: 6 col-blocks sharing an A M-tile run time-adjacent on one XCD.
#define BM 128
#define BNB 128
#define BK 32
#define NCOLB (NC / BNB) /* 6 */
#define NMT (RTOT / BM)  /* 512 */
__global__ __launch_bounds__(256, 4) void k_gemm1(
    const unsigned short* __restrict__ xb, const unsigned short* __restrict__ wt,
    const float* __restrict__ g_b, const float* __restrict__ f_b,
    unsigned short* __restrict__ E, unsigned short* __restrict__ FXB) {
  __shared__ __attribute__((aligned(16))) unsigned short As[BM * BK]; // 8 KB
  __shared__ __attribute__((aligned(16))) unsigned short Bs[BNB * BK];

  // bijective XCD swizzle (3072 % 8 == 0): per-XCD, col varies fastest
  const int wg = blockIdx.x;            // 0..3071
  const int xcd = wg & 7;
  const int ix = wg >> 3;               // 0..383
  const int mt = xcd * (NMT / 8) + ix / NCOLB;
  const int colb = ix % NCOLB;
  const int row0 = mt * BM, col0 = colb * BNB;

  const int tid = threadIdx.x;
  const int lane = tid & 63, wid = tid >> 6;
  const int wr = wid >> 1, wc = wid & 1;

  // staging addresses: wave wid, call j in {0,1} covers LDS bytes
  // [wid*2048 + j*1024, +1024); lane l -> 16B at +l*16
  // => tile row = wid*32 + j*16 + l/4, k-bytes = (l%4)*16
  const int srow = wid * 32 + (lane >> 2);
  const int skb = (lane & 3) * 16;
  const char* aSrc = (const char*)xb + ((size_t)(row0 + srow)) * (D * 2) + skb;
  const char* bSrc = (const char*)wt + ((size_t)(col0 + srow)) * (D * 2) + skb;
  char* aDst = (char*)As + wid * 2048 + (lane & 3) * 0; // wave-uniform base
  char* bDst = (char*)Bs + wid * 2048;
  aDst = (char*)As + wid * 2048;

  f32x4 acc[4][4];
#pragma unroll
  for (int m = 0; m < 4; m++)
#pragma unroll
    for (int n = 0; n < 4; n++) acc[m][n] = (f32x4){0.f, 0.f, 0.f, 0.f};

#pragma unroll 1
  for (int kt = 0; kt < D / BK; kt++) {
    const int kb = kt * (BK * 2); // byte offset along K
    __syncthreads(); // previous iteration's ds_reads done before overwrite
    gl16(aSrc + kb, aDst);
    gl16(aSrc + 16 * (D * 2) + kb, aDst + 1024);
    gl16(bSrc + kb, bDst);
    gl16(bSrc + 16 * (D * 2) + kb, bDst + 1024);
    __syncthreads(); // compiler drains vmcnt(0) here -> staged data visible

    bf16x8 af[4], bfr[4];
#pragma unroll
    for (int m = 0; m < 4; m++)
      af[m] = *(const bf16x8*)(As + (wr * 64 + m * 16 + (lane & 15)) * BK + (lane >> 4) * 8);
#pragma unroll
    for (int n = 0; n < 4; n++)
      bfr[n] = *(const bf16x8*)(Bs + (wc * 64 + n * 16 + (lane & 15)) * BK + (lane >> 4) * 8);
#pragma unroll
    for (int m = 0; m < 4; m++)
#pragma unroll
      for (int n = 0; n < 4; n++)
        acc[m][n] = __builtin_amdgcn_mfma_f32_16x16x32_bf16(af[m], bfr[n], acc[m][n], 0, 0, 0);
  }

  const bool isG = (col0 < D); // block-uniform: cols [0,384) -> E, [384,768) -> FXB
#pragma unroll
  for (int m = 0; m < 4; m++) {
    const int grow0 = row0 + wr * 64 + m * 16 + ((lane >> 4) * 4);
#pragma unroll
    for (int n = 0; n < 4; n++) {
      const int gcol = col0 + wc * 64 + n * 16 + (lane & 15);
#pragma unroll
      for (int r = 0; r < 4; r++) {
        const int grow = grow0 + r;
        const float v = acc[m][n][r];
        if (isG) {
          E[(size_t)grow * D + gcol] = f2bf(expf(v + g_b[gcol]));
        } else {
          FXB[(size_t)grow * D + (gcol - D)] = f2bf(v + f_b[gcol - D]);
        }
      }
    }
  }
}

// ---------------- segment sums + divide (uint = 2 bf16 per lane) ----------------
__global__ __launch_bounds__(192) void k_seg(
    const unsigned short* __restrict__ E, const unsigned short* __restrict__ FXB,
    const int* __restrict__ csr_start, const int* __restrict__ csr_rows,
    unsigned short* __restrict__ ypre) {
  const int m = blockIdx.x, b = blockIdx.y, t = threadIdx.x; // t in [0,192)
  const int s = csr_start[m], e = csr_start[m + 1];
  const unsigned int* E32 = (const unsigned int*)E;
  const unsigned int* F32 = (const unsigned int*)FXB;
  float s1x = 0.f, s1y = 0.f, s2x = 0.f, s2y = 0.f;
  for (int i = s; i < e; i++) {
    const int n = csr_rows[i];
    const size_t off = ((size_t)(b * NROWS + n)) * (D / 2) + t;
    const unsigned int ev = E32[off];
    const unsigned int fv = F32[off];
    const float e0 = bf2f((unsigned short)(ev & 0xffff));
    const float e1 = bf2f((unsigned short)(ev >> 16));
    const float f0 = bf2f((unsigned short)(fv & 0xffff));
    const float f1 = bf2f((unsigned short)(fv >> 16));
    s1x += e0; s1y += e1;
    s2x += f0 * e0; s2y += f1 * e1;
  }
  const float y0 = s2x / (s1x + 1e-6f);
  const float y1 = s2y / (s1y + 1e-6f);
  ((unsigned int*)ypre)[((size_t)(b * MG + m)) * (D / 2) + t] =
      (unsigned int)f2bf(y0) | ((unsigned int)f2bf(y1) << 16);
}

// ---------------- small GEMM: Outpre = Ypre @ h_w^T + h_b ----------------
__global__ __launch_bounds__(256) void k_gemm2(
    const unsigned short* __restrict__ ypre, const unsigned short* __restrict__ hw,
    const float* __restrict__ h_b, float* __restrict__ outpre) {
  const int tid = threadIdx.x, lane = tid & 63, wid = tid >> 6;
  const int r0 = blockIdx.y * 16;
  const int c0 = blockIdx.x * 64 + wid * 16;
  f32x4 acc = (f32x4){0.f, 0.f, 0.f, 0.f};
  const unsigned short* aRow = ypre + (size_t)(r0 + (lane & 15)) * D + (lane >> 4) * 8;
  const unsigned short* bRow = hw + (size_t)(c0 + (lane & 15)) * D + (lane >> 4) * 8;
#pragma unroll
  for (int kt = 0; kt < D / 32; kt++) {
    bf16x8 af = *(const bf16x8*)(aRow + kt * 32);
    bf16x8 bf_ = *(const bf16x8*)(bRow + kt * 32);
    acc = __builtin_amdgcn_mfma_f32_16x16x32_bf16(af, bf_, acc, 0, 0, 0);
  }
  const int col = c0 + (lane & 15);
  const float hb = h_b[col];
#pragma unroll
  for (int r = 0; r < 4; r++) {
    const int row = r0 + (lane >> 4) * 4 + r;
    outpre[(size_t)row * D + col] = acc[r] + hb;
  }
}

// ---------------- gather rows ----------------
__global__ void k_gather(const float* __restrict__ outpre, const int* __restrict__ ii,
                         float* __restrict__ out) {
  const long total4 = (long)RTOT * (D / 4); // 96 float4 per row
  for (long i = blockIdx.x * (long)blockDim.x + threadIdx.x; i < total4;
       i += (long)gridDim.x * blockDim.x) {
    const long row = i / (D / 4);
    const int q = (int)(i % (D / 4));
    const int b = (int)(row >> 14);
    const int n = (int)(row & (NROWS - 1));
    const int g = ii[n];
    ((float4*)out)[i] = ((const float4*)outpre)[((size_t)(b * MG + g)) * (D / 4) + q];
  }
}

extern "C" void kernel_launch(void* const* d_in, const int* in_sizes, int n_in,
                              void* d_out, int out_size, void* d_ws, size_t ws_size,
                              hipStream_t stream) {
  const float* x = (const float*)d_in[0];
  const int* ii = (const int*)d_in[1];
  const float* f_w = (const float*)d_in[2];
  const float* f_b = (const float*)d_in[3];
  const float* g_w = (const float*)d_in[4];
  const float* g_b = (const float*)d_in[5];
  const float* h_w = (const float*)d_in[6];
  const float* h_b = (const float*)d_in[7];
  float* out = (float*)d_out;

  char* ws = (char*)d_ws;
  size_t off = 0;
  auto alloc = [&](size_t bytes) {
    size_t p = off;
    off = (off + bytes + 255) & ~(size_t)255;
    return p;
  };
  unsigned short* xb = (unsigned short*)(ws + alloc((size_t)RTOT * D * 2));
  unsigned short* wt = (unsigned short*)(ws + alloc((size_t)NC * D * 2));
  unsigned short* hw = (unsigned short*)(ws + alloc((size_t)D * D * 2));
  unsigned short* E = (unsigned short*)(ws + alloc((size_t)RTOT * D * 2));
  unsigned short* FXB = (unsigned short*)(ws + alloc((size_t)RTOT * D * 2));
  unsigned short* ypre = (unsigned short*)(ws + alloc((size_t)BATCH * MG * D * 2));
  float* outpre = (float*)(ws + alloc((size_t)BATCH * MG * D * 4));
  int* csr_start = (int*)(ws + alloc((MG + 1) * 4));
  int* csr_rows = (int*)(ws + alloc((size_t)NROWS * 4));

  k_convert_x<<<dim3(4096), dim3(256), 0, stream>>>(x, xb);
  k_build_w<<<dim3(1152), dim3(256), 0, stream>>>(g_w, f_w, h_w, wt, hw);
  k_csr<<<dim3(1), dim3(MG), 0, stream>>>(ii, csr_start, csr_rows);
  k_gemm1<<<dim3(NCOLB * NMT), dim3(256), 0, stream>>>(xb, wt, g_b, f_b, E, FXB);
  k_seg<<<dim3(MG, BATCH), dim3(192), 0, stream>>>(E, FXB, csr_start, csr_rows, ypre);
  k_gemm2<<<dim3(D / 64, (BATCH * MG) / 16), dim3(256), 0, stream>>>(ypre, hw, h_b, outpre);
  k_gather<<<dim3(4096), dim3(256), 0, stream>>>(outpre, ii, out);
}

// Round 3
// 160.843 us; speedup vs baseline: 1.6460x; 1.2282x over previous
//
#include <hip/hip_runtime.h>
#include <hip/hip_bf16.h>

#define D 384
#define NROWS 16384
#define BATCH 4
#define MG 512
#define RTOT (BATCH * NROWS) /* 65536 */
#define NC (2 * D)           /* 768 combined B rows: interleaved g|f panels */
#define JB 64                /* j-columns per block */
#define NJB (D / JB)         /* 6 */
#define BM 128
#define BK 32
#define NKT (D / BK)         /* 12 */
#define NMT (RTOT / BM)      /* 512 */

typedef __attribute__((ext_vector_type(8))) short bf16x8;
typedef __attribute__((ext_vector_type(4))) float f32x4;

static __device__ __forceinline__ unsigned short f2bf(float f) {
  unsigned int u = __float_as_uint(f);
  unsigned int r = u + 0x7fffu + ((u >> 16) & 1u); // RNE
  return (unsigned short)(r >> 16);
}
static __device__ __forceinline__ float bf2f(unsigned short h) {
  return __uint_as_float(((unsigned int)h) << 16);
}

typedef __attribute__((address_space(1))) const void gvoid_t;
typedef __attribute__((address_space(3))) void lvoid_t;
static __device__ __forceinline__ void gl16(const void* g, void* l) {
  __builtin_amdgcn_global_load_lds((gvoid_t*)g, (lvoid_t*)l, 16, 0, 0);
}

// ---------------- x f32 -> bf16 ----------------
__global__ void k_convert_x(const float* __restrict__ x, unsigned short* __restrict__ xb) {
  const long total4 = (long)RTOT * D / 4;
  for (long i = blockIdx.x * (long)blockDim.x + threadIdx.x; i < total4;
       i += (long)gridDim.x * blockDim.x) {
    float4 v = ((const float4*)x)[i];
    ushort4 o;
    o.x = f2bf(v.x); o.y = f2bf(v.y); o.z = f2bf(v.z); o.w = f2bf(v.w);
    ((ushort4*)xb)[i] = o;
  }
}

// wt2: per j-block panel of 128 rows: rows 0..63 = g_w[j0+c], rows 64..127 = f_w[j0+c-64]
__global__ void k_build_w(const float* __restrict__ g_w, const float* __restrict__ f_w,
                          const float* __restrict__ h_w,
                          unsigned short* __restrict__ wt2, unsigned short* __restrict__ hw) {
  const int totW = NC * D, totH = D * D;
  int tid0 = blockIdx.x * blockDim.x + threadIdx.x;
  int stride = gridDim.x * blockDim.x;
  for (int idx = tid0; idx < totW; idx += stride) {
    int jblk = idx / (128 * D);
    int rem = idx % (128 * D);
    int c = rem / D, k = rem % D;
    int j = jblk * JB + (c & 63);
    float v = (c < JB) ? g_w[j * D + k] : f_w[j * D + k];
    wt2[idx] = f2bf(v);
  }
  for (int idx = tid0; idx < totH; idx += stride) hw[idx] = f2bf(h_w[idx]);
}

// ---------------- CSR build (one block): rows sorted by group ----------------
__global__ void k_csr(const int* __restrict__ ii, int* __restrict__ csr_start,
                      int* __restrict__ csr_rows, int* __restrict__ grp_sorted) {
  __shared__ int cnt[MG];
  int t = threadIdx.x; // 512 threads
  cnt[t] = 0;
  __syncthreads();
  for (int n = t; n < NROWS; n += MG) atomicAdd(&cnt[ii[n]], 1);
  __syncthreads();
  if (t == 0) {
    int run = 0;
    for (int i = 0; i < MG; i++) {
      int c = cnt[i];
      cnt[i] = run;
      csr_start[i] = run;
      run += c;
    }
    csr_start[MG] = run;
  }
  __syncthreads();
  for (int n = t; n < NROWS; n += MG) {
    int m = ii[n];
    int pos = atomicAdd(&cnt[m], 1);
    csr_rows[pos] = n;
    grp_sorted[pos] = m;
  }
}

// ---------------- fused GEMM + exp + segment-reduce ----------------
// Block: 128 CSR-ordered rows (one batch) x 64 j-cols (g AND f halves).
// 2-phase double-buffered K-loop; epilogue reduces per-group in-wave and
// atomicAdds f32 partials into s1acc/s2acc.
__global__ __launch_bounds__(256, 4) void k_gemm1(
    const unsigned short* __restrict__ xb, const unsigned short* __restrict__ wt2,
    const float* __restrict__ g_b, const float* __restrict__ f_b,
    const int* __restrict__ csr_rows, const int* __restrict__ grp_sorted,
    float* __restrict__ s1acc, float* __restrict__ s2acc) {
  __shared__ __attribute__((aligned(16))) unsigned short As[2][BM * BK]; // 2 x 8 KB
  __shared__ __attribute__((aligned(16))) unsigned short Bs[2][BM * BK];
  __shared__ int grpS[BM];

  // bijective XCD swizzle; j-block varies fastest within an XCD (A-tile L2 reuse)
  const int wg = blockIdx.x; // 0..3071
  const int xcd = wg & 7;
  const int ix = wg >> 3; // 0..383
  const int mt = xcd * (NMT / 8) + ix / NJB;
  const int jb = ix % NJB;
  const int b = mt >> 7;            // batch
  const int ib = (mt & 127) * BM;   // per-batch CSR base index
  const int j0 = jb * JB;

  const int tid = threadIdx.x;
  const int lane = tid & 63, wid = tid >> 6;
  const int wr = wid >> 1, wc = wid & 1;

  if (tid < BM) grpS[tid] = grp_sorted[ib + tid];

  // staging: wave wid covers LDS rows wid*32..+31 (two 16-row chunks)
  const int srow = wid * 32 + (lane >> 2);
  const int skb = (lane & 3) * 16;
  const int arow0 = b * NROWS + csr_rows[ib + srow];
  const int arow1 = b * NROWS + csr_rows[ib + srow + 16];
  const char* aS0 = (const char*)xb + (size_t)arow0 * (D * 2) + skb;
  const char* aS1 = (const char*)xb + (size_t)arow1 * (D * 2) + skb;
  const char* bS0 = (const char*)wt2 + (size_t)jb * (128 * D * 2) + (size_t)srow * (D * 2) + skb;
  const char* bS1 = bS0 + 16 * (D * 2);

  f32x4 acc[4][4];
#pragma unroll
  for (int m = 0; m < 4; m++)
#pragma unroll
    for (int n = 0; n < 4; n++) acc[m][n] = (f32x4){0.f, 0.f, 0.f, 0.f};

  // prologue: stage kt=0 into buf 0
  {
    char* ad = (char*)As[0] + wid * 2048;
    char* bd = (char*)Bs[0] + wid * 2048;
    gl16(aS0, ad); gl16(aS1, ad + 1024);
    gl16(bS0, bd); gl16(bS1, bd + 1024);
  }
  __syncthreads();

#pragma unroll 1
  for (int kt = 0; kt < NKT; ++kt) {
    const int cur = kt & 1;
    if (kt < NKT - 1) { // stage next tile into other buffer BEFORE compute
      const int kb = (kt + 1) * (BK * 2);
      char* ad = (char*)As[cur ^ 1] + wid * 2048;
      char* bd = (char*)Bs[cur ^ 1] + wid * 2048;
      gl16(aS0 + kb, ad); gl16(aS1 + kb, ad + 1024);
      gl16(bS0 + kb, bd); gl16(bS1 + kb, bd + 1024);
    }
    bf16x8 af[4], bfv[4];
#pragma unroll
    for (int m = 0; m < 4; m++)
      af[m] = *(const bf16x8*)(&As[cur][(wr * 64 + m * 16 + (lane & 15)) * BK + (lane >> 4) * 8]);
#pragma unroll
    for (int n = 0; n < 4; n++) {
      const int c = (n < 2) ? (wc * 32 + n * 16) : (64 + wc * 32 + (n - 2) * 16);
      bfv[n] = *(const bf16x8*)(&Bs[cur][(c + (lane & 15)) * BK + (lane >> 4) * 8]);
    }
#pragma unroll
    for (int m = 0; m < 4; m++)
#pragma unroll
      for (int n = 0; n < 4; n++)
        acc[m][n] = __builtin_amdgcn_mfma_f32_16x16x32_bf16(af[m], bfv[n], acc[m][n], 0, 0, 0);
    __syncthreads(); // drains vmcnt(0) too: next buffer staged & visible
  }

  // ---- epilogue: e = exp(logit+gb); fxe = (fx+fb)*e; per-group reduce ----
  const int jc = lane & 15;
  const int jA = j0 + wc * 32 + jc; // cols for n=0 (g) / n=2 (f)
  const float gb0 = g_b[jA], gb1 = g_b[jA + 16];
  const float fb0 = f_b[jA], fb1 = f_b[jA + 16];

  int gmr[4][4];
#pragma unroll
  for (int m = 0; m < 4; m++)
#pragma unroll
    for (int r = 0; r < 4; r++)
      gmr[m][r] = grpS[wr * 64 + m * 16 + (lane >> 4) * 4 + r];

#pragma unroll
  for (int m = 0; m < 4; m++)
#pragma unroll
    for (int r = 0; r < 4; r++) {
      const float e0 = expf(acc[m][0][r] + gb0);
      const float e1 = expf(acc[m][1][r] + gb1);
      const float f0 = acc[m][2][r] + fb0;
      const float f1 = acc[m][3][r] + fb1;
      acc[m][0][r] = e0; acc[m][1][r] = e1;
      acc[m][2][r] = f0 * e0; acc[m][3][r] = f1 * e1;
    }

  const int gLo = grpS[wr * 64], gHi = grpS[wr * 64 + 63];
  for (int g = gLo; g <= gHi; ++g) {
    float v0 = 0.f, v1 = 0.f, v2 = 0.f, v3 = 0.f;
#pragma unroll
    for (int m = 0; m < 4; m++)
#pragma unroll
      for (int r = 0; r < 4; r++)
        if (gmr[m][r] == g) {
          v0 += acc[m][0][r]; v1 += acc[m][1][r];
          v2 += acc[m][2][r]; v3 += acc[m][3][r];
        }
    v0 += __shfl_xor(v0, 16); v0 += __shfl_xor(v0, 32);
    v1 += __shfl_xor(v1, 16); v1 += __shfl_xor(v1, 32);
    v2 += __shfl_xor(v2, 16); v2 += __shfl_xor(v2, 32);
    v3 += __shfl_xor(v3, 16); v3 += __shfl_xor(v3, 32);
    if (lane < 16) {
      float* s1p = s1acc + ((size_t)(b * MG + g)) * D + j0 + wc * 32 + lane;
      float* s2p = s2acc + ((size_t)(b * MG + g)) * D + j0 + wc * 32 + lane;
      atomicAdd(s1p, v0);
      atomicAdd(s1p + 16, v1);
      atomicAdd(s2p, v2);
      atomicAdd(s2p + 16, v3);
    }
  }
}

// ---------------- ypre = s2/(s1+eps) -> bf16 ----------------
__global__ __launch_bounds__(256) void k_norm(const float* __restrict__ s1,
                                              const float* __restrict__ s2,
                                              unsigned short* __restrict__ ypre) {
  const int i = blockIdx.x * blockDim.x + threadIdx.x; // exact grid
  ypre[i] = f2bf(s2[i] / (s1[i] + 1e-6f));
}

// ---------------- small GEMM: Outpre = Ypre @ h_w^T + h_b ----------------
__global__ __launch_bounds__(256) void k_gemm2(
    const unsigned short* __restrict__ ypre, const unsigned short* __restrict__ hw,
    const float* __restrict__ h_b, float* __restrict__ outpre) {
  const int tid = threadIdx.x, lane = tid & 63, wid = tid >> 6;
  const int r0 = blockIdx.y * 16;
  const int c0 = blockIdx.x * 64 + wid * 16;
  f32x4 acc = (f32x4){0.f, 0.f, 0.f, 0.f};
  const unsigned short* aRow = ypre + (size_t)(r0 + (lane & 15)) * D + (lane >> 4) * 8;
  const unsigned short* bRow = hw + (size_t)(c0 + (lane & 15)) * D + (lane >> 4) * 8;
#pragma unroll
  for (int kt = 0; kt < D / 32; kt++) {
    bf16x8 af = *(const bf16x8*)(aRow + kt * 32);
    bf16x8 bf_ = *(const bf16x8*)(bRow + kt * 32);
    acc = __builtin_amdgcn_mfma_f32_16x16x32_bf16(af, bf_, acc, 0, 0, 0);
  }
  const int col = c0 + (lane & 15);
  const float hb = h_b[col];
#pragma unroll
  for (int r = 0; r < 4; r++) {
    const int row = r0 + (lane >> 4) * 4 + r;
    outpre[(size_t)row * D + col] = acc[r] + hb;
  }
}

// ---------------- gather rows ----------------
__global__ void k_gather(const float* __restrict__ outpre, const int* __restrict__ ii,
                         float* __restrict__ out) {
  const long total4 = (long)RTOT * (D / 4); // 96 float4 per row
  for (long i = blockIdx.x * (long)blockDim.x + threadIdx.x; i < total4;
       i += (long)gridDim.x * blockDim.x) {
    const long row = i / (D / 4);
    const int q = (int)(i % (D / 4));
    const int b = (int)(row >> 14);
    const int n = (int)(row & (NROWS - 1));
    const int g = ii[n];
    ((float4*)out)[i] = ((const float4*)outpre)[((size_t)(b * MG + g)) * (D / 4) + q];
  }
}

extern "C" void kernel_launch(void* const* d_in, const int* in_sizes, int n_in,
                              void* d_out, int out_size, void* d_ws, size_t ws_size,
                              hipStream_t stream) {
  const float* x = (const float*)d_in[0];
  const int* ii = (const int*)d_in[1];
  const float* f_w = (const float*)d_in[2];
  const float* f_b = (const float*)d_in[3];
  const float* g_w = (const float*)d_in[4];
  const float* g_b = (const float*)d_in[5];
  const float* h_w = (const float*)d_in[6];
  const float* h_b = (const float*)d_in[7];
  float* out = (float*)d_out;

  char* ws = (char*)d_ws;
  size_t off = 0;
  auto alloc = [&](size_t bytes) {
    size_t p = off;
    off = (off + bytes + 255) & ~(size_t)255;
    return p;
  };
  unsigned short* xb = (unsigned short*)(ws + alloc((size_t)RTOT * D * 2));
  unsigned short* wt2 = (unsigned short*)(ws + alloc((size_t)NC * D * 2));
  unsigned short* hw = (unsigned short*)(ws + alloc((size_t)D * D * 2));
  float* s1acc = (float*)(ws + alloc((size_t)BATCH * MG * D * 4)); // 3 MB
  float* s2acc = (float*)(ws + alloc((size_t)BATCH * MG * D * 4)); // contiguous after s1acc
  unsigned short* ypre = (unsigned short*)(ws + alloc((size_t)BATCH * MG * D * 2));
  float* outpre = (float*)(ws + alloc((size_t)BATCH * MG * D * 4));
  int* csr_start = (int*)(ws + alloc((MG + 1) * 4));
  int* csr_rows = (int*)(ws + alloc((size_t)NROWS * 4));
  int* grp_sorted = (int*)(ws + alloc((size_t)NROWS * 4));

  hipMemsetAsync(s1acc, 0, (size_t)2 * BATCH * MG * D * 4, stream); // s1acc+s2acc

  k_convert_x<<<dim3(4096), dim3(256), 0, stream>>>(x, xb);
  k_build_w<<<dim3(1152), dim3(256), 0, stream>>>(g_w, f_w, h_w, wt2, hw);
  k_csr<<<dim3(1), dim3(MG), 0, stream>>>(ii, csr_start, csr_rows, grp_sorted);
  k_gemm1<<<dim3(NJB * NMT), dim3(256), 0, stream>>>(xb, wt2, g_b, f_b, csr_rows,
                                                     grp_sorted, s1acc, s2acc);
  k_norm<<<dim3((BATCH * MG * D) / 256), dim3(256), 0, stream>>>(s1acc, s2acc, ypre);
  k_gemm2<<<dim3(D / 64, (BATCH * MG) / 16), dim3(256), 0, stream>>>(ypre, hw, h_b, outpre);
  k_gather<<<dim3(4096), dim3(256), 0, stream>>>(outpre, ii, out);
}

// Round 4
// 146.608 us; speedup vs baseline: 1.8058x; 1.0971x over previous
//
#include <hip/hip_runtime.h>
#include <hip/hip_bf16.h>

#define D 384
#define NROWS 16384
#define BATCH 4
#define MG 512
#define RTOT (BATCH * NROWS) /* 65536 */
#define NC (2 * D)           /* 768 combined B rows: g|f panels per j-block */
#define JB 64                /* j-columns per block */
#define NJB (D / JB)         /* 6 */
#define BM 128
#define BK 32
#define NKT (D / BK)         /* 12 */
#define NMT (RTOT / BM)      /* 512 */

typedef __attribute__((ext_vector_type(8))) short bf16x8;
typedef __attribute__((ext_vector_type(4))) float f32x4;

static __device__ __forceinline__ unsigned short f2bf(float f) {
  unsigned int u = __float_as_uint(f);
  unsigned int r = u + 0x7fffu + ((u >> 16) & 1u); // RNE
  return (unsigned short)(r >> 16);
}
static __device__ __forceinline__ unsigned int cvtpk(float lo, float hi) {
  unsigned int r;
  asm("v_cvt_pk_bf16_f32 %0, %1, %2" : "=v"(r) : "v"(lo), "v"(hi));
  return r;
}
static __device__ __forceinline__ float frcp(float f) {
  float r;
  asm("v_rcp_f32 %0, %1" : "=v"(r) : "v"(f));
  return r;
}

typedef __attribute__((address_space(1))) const void gvoid_t;
typedef __attribute__((address_space(3))) void lvoid_t;
static __device__ __forceinline__ void gl16(const void* g, void* l) {
  __builtin_amdgcn_global_load_lds((gvoid_t*)g, (lvoid_t*)l, 16, 0, 0);
}

// wt2: per j-block panel of 128 rows: rows 0..63 = g_w[j0+c], rows 64..127 = f_w[j0+c-64]
__global__ void k_build_w(const float* __restrict__ g_w, const float* __restrict__ f_w,
                          const float* __restrict__ h_w,
                          unsigned short* __restrict__ wt2, unsigned short* __restrict__ hw) {
  const int totW = NC * D, totH = D * D;
  int tid0 = blockIdx.x * blockDim.x + threadIdx.x;
  int stride = gridDim.x * blockDim.x;
  for (int idx = tid0; idx < totW; idx += stride) {
    int jblk = idx / (128 * D);
    int rem = idx % (128 * D);
    int c = rem / D, k = rem % D;
    int j = jblk * JB + (c & 63);
    float v = (c < JB) ? g_w[j * D + k] : f_w[j * D + k];
    wt2[idx] = f2bf(v);
  }
  for (int idx = tid0; idx < totH; idx += stride) hw[idx] = f2bf(h_w[idx]);
}

// ---------------- CSR build (one block, parallel scan) ----------------
__global__ void k_csr(const int* __restrict__ ii, int* __restrict__ csr_start,
                      int* __restrict__ csr_rows, int* __restrict__ grp_sorted) {
  __shared__ int cnt[MG];
  __shared__ int scan[MG];
  const int t = threadIdx.x; // 512 threads
  cnt[t] = 0;
  __syncthreads();
  for (int n = t; n < NROWS; n += MG) atomicAdd(&cnt[ii[n]], 1);
  __syncthreads();
  const int v = cnt[t];
  scan[t] = v;
  __syncthreads();
#pragma unroll
  for (int o = 1; o < MG; o <<= 1) { // Hillis-Steele inclusive scan
    int u = (t >= o) ? scan[t - o] : 0;
    __syncthreads();
    scan[t] += u;
    __syncthreads();
  }
  const int excl = scan[t] - v;
  csr_start[t] = excl;
  if (t == MG - 1) csr_start[MG] = scan[t];
  cnt[t] = excl;
  __syncthreads();
  for (int n = t; n < NROWS; n += MG) {
    int m = ii[n];
    int pos = atomicAdd(&cnt[m], 1);
    csr_rows[pos] = n;
    grp_sorted[pos] = m;
  }
}

// ---------------- fused GEMM + exp + segment-reduce ----------------
// A staged straight from f32 x (reg-stage + cvt_pk, loads issued a step ahead);
// B via global_load_lds. 2-phase double-buffered K-loop. Epilogue reduces
// per-group in-wave, atomicAdds f32 partials into s1acc/s2acc.
__global__ __launch_bounds__(256, 4) void k_gemm1(
    const float* __restrict__ x, const unsigned short* __restrict__ wt2,
    const float* __restrict__ g_b, const float* __restrict__ f_b,
    const int* __restrict__ csr_rows, const int* __restrict__ grp_sorted,
    float* __restrict__ s1acc, float* __restrict__ s2acc) {
  __shared__ __attribute__((aligned(16))) unsigned short As[2][BM * BK]; // 2 x 8 KB
  __shared__ __attribute__((aligned(16))) unsigned short Bs[2][BM * BK];
  __shared__ int grpS[BM];

  // bijective XCD swizzle; j-block varies fastest within an XCD (A-tile L2 reuse)
  const int wg = blockIdx.x; // 0..3071
  const int xcd = wg & 7;
  const int ix = wg >> 3; // 0..383
  const int mt = xcd * (NMT / 8) + ix / NJB;
  const int jb = ix % NJB;
  const int b = mt >> 7;          // batch
  const int ib = (mt & 127) * BM; // per-batch CSR base index
  const int j0 = jb * JB;

  const int tid = threadIdx.x;
  const int lane = tid & 63, wid = tid >> 6;
  const int wr = wid >> 1, wc = wid & 1;

  if (tid < BM) grpS[tid] = grp_sorted[ib + tid];

  // staging geometry: wave wid covers tile rows wid*32..+31 as two 16-row
  // chunks; lane l -> row wid*32 + (l>>2) (+16), k-chunk (l&3).
  const int srow = wid * 32 + (lane >> 2);
  const int arow0 = b * NROWS + csr_rows[ib + srow];
  const int arow1 = b * NROWS + csr_rows[ib + srow + 16];
  const char* aS0 = (const char*)x + (size_t)arow0 * (D * 4) + (lane & 3) * 32;
  const char* aS1 = (const char*)x + (size_t)arow1 * (D * 4) + (lane & 3) * 32;
  const char* bS0 = (const char*)wt2 + (size_t)jb * (128 * D * 2) + (size_t)srow * (D * 2) +
                    (lane & 3) * 16;
  const char* bS1 = bS0 + 16 * (D * 2);

  f32x4 acc[4][4];
#pragma unroll
  for (int m = 0; m < 4; m++)
#pragma unroll
    for (int n = 0; n < 4; n++) acc[m][n] = (f32x4){0.f, 0.f, 0.f, 0.f};

  // prologue: stage kt=0 into buf 0
  float4 a00 = *(const float4*)(aS0);
  float4 a01 = *(const float4*)(aS0 + 16);
  float4 a10 = *(const float4*)(aS1);
  float4 a11 = *(const float4*)(aS1 + 16);
  {
    char* bd = (char*)Bs[0] + wid * 2048;
    gl16(bS0, bd);
    gl16(bS1, bd + 1024);
    int4 p0, p1;
    p0.x = cvtpk(a00.x, a00.y); p0.y = cvtpk(a00.z, a00.w);
    p0.z = cvtpk(a01.x, a01.y); p0.w = cvtpk(a01.z, a01.w);
    p1.x = cvtpk(a10.x, a10.y); p1.y = cvtpk(a10.z, a10.w);
    p1.z = cvtpk(a11.x, a11.y); p1.w = cvtpk(a11.z, a11.w);
    *(int4*)((char*)As[0] + wid * 2048 + lane * 16) = p0;
    *(int4*)((char*)As[0] + wid * 2048 + 1024 + lane * 16) = p1;
  }
  __syncthreads();

#pragma unroll 1
  for (int kt = 0; kt < NKT; ++kt) {
    const int cur = kt & 1;
    const bool more = (kt < NKT - 1);
    if (more) { // issue next-tile loads BEFORE compute (latency hides under MFMA)
      const int kbf = (kt + 1) * (BK * 4);
      const int kbb = (kt + 1) * (BK * 2);
      a00 = *(const float4*)(aS0 + kbf);
      a01 = *(const float4*)(aS0 + kbf + 16);
      a10 = *(const float4*)(aS1 + kbf);
      a11 = *(const float4*)(aS1 + kbf + 16);
      char* bd = (char*)Bs[cur ^ 1] + wid * 2048;
      gl16(bS0 + kbb, bd);
      gl16(bS1 + kbb, bd + 1024);
    }
    bf16x8 af[4], bfv[4];
#pragma unroll
    for (int m = 0; m < 4; m++)
      af[m] = *(const bf16x8*)(&As[cur][(wr * 64 + m * 16 + (lane & 15)) * BK + (lane >> 4) * 8]);
#pragma unroll
    for (int n = 0; n < 4; n++) {
      const int c = (n < 2) ? (wc * 32 + n * 16) : (64 + wc * 32 + (n - 2) * 16);
      bfv[n] = *(const bf16x8*)(&Bs[cur][(c + (lane & 15)) * BK + (lane >> 4) * 8]);
    }
#pragma unroll
    for (int m = 0; m < 4; m++)
#pragma unroll
      for (int n = 0; n < 4; n++)
        acc[m][n] = __builtin_amdgcn_mfma_f32_16x16x32_bf16(af[m], bfv[n], acc[m][n], 0, 0, 0);
    if (more) { // convert + LDS-write after compute, before barrier
      int4 p0, p1;
      p0.x = cvtpk(a00.x, a00.y); p0.y = cvtpk(a00.z, a00.w);
      p0.z = cvtpk(a01.x, a01.y); p0.w = cvtpk(a01.z, a01.w);
      p1.x = cvtpk(a10.x, a10.y); p1.y = cvtpk(a10.z, a10.w);
      p1.z = cvtpk(a11.x, a11.y); p1.w = cvtpk(a11.z, a11.w);
      *(int4*)((char*)As[cur ^ 1] + wid * 2048 + lane * 16) = p0;
      *(int4*)((char*)As[cur ^ 1] + wid * 2048 + 1024 + lane * 16) = p1;
    }
    __syncthreads();
  }

  // ---- epilogue: e = exp(logit+gb); fxe = (fx+fb)*e; per-group reduce ----
  const int jc = lane & 15;
  const int jA = j0 + wc * 32 + jc; // cols for n=0 (g) / n=2 (f)
  const float gb0 = g_b[jA], gb1 = g_b[jA + 16];
  const float fb0 = f_b[jA], fb1 = f_b[jA + 16];

  int gmr[4][4];
#pragma unroll
  for (int m = 0; m < 4; m++)
#pragma unroll
    for (int r = 0; r < 4; r++)
      gmr[m][r] = grpS[wr * 64 + m * 16 + (lane >> 4) * 4 + r];

#pragma unroll
  for (int m = 0; m < 4; m++)
#pragma unroll
    for (int r = 0; r < 4; r++) {
      const float e0 = expf(acc[m][0][r] + gb0);
      const float e1 = expf(acc[m][1][r] + gb1);
      const float f0 = acc[m][2][r] + fb0;
      const float f1 = acc[m][3][r] + fb1;
      acc[m][0][r] = e0; acc[m][1][r] = e1;
      acc[m][2][r] = f0 * e0; acc[m][3][r] = f1 * e1;
    }

  const int gLo = grpS[wr * 64], gHi = grpS[wr * 64 + 63];
  for (int g = gLo; g <= gHi; ++g) {
    float v0 = 0.f, v1 = 0.f, v2 = 0.f, v3 = 0.f;
#pragma unroll
    for (int m = 0; m < 4; m++)
#pragma unroll
      for (int r = 0; r < 4; r++)
        if (gmr[m][r] == g) {
          v0 += acc[m][0][r]; v1 += acc[m][1][r];
          v2 += acc[m][2][r]; v3 += acc[m][3][r];
        }
    v0 += __shfl_xor(v0, 16); v0 += __shfl_xor(v0, 32);
    v1 += __shfl_xor(v1, 16); v1 += __shfl_xor(v1, 32);
    v2 += __shfl_xor(v2, 16); v2 += __shfl_xor(v2, 32);
    v3 += __shfl_xor(v3, 16); v3 += __shfl_xor(v3, 32);
    if (lane < 16) {
      float* s1p = s1acc + ((size_t)(b * MG + g)) * D + j0 + wc * 32 + lane;
      float* s2p = s2acc + ((size_t)(b * MG + g)) * D + j0 + wc * 32 + lane;
      atomicAdd(s1p, v0);
      atomicAdd(s1p + 16, v1);
      atomicAdd(s2p, v2);
      atomicAdd(s2p + 16, v3);
    }
  }
}

// ---------------- small GEMM with fused normalize: Outpre = (s2/(s1+eps)) @ h_w^T + h_b ----------------
__global__ __launch_bounds__(256) void k_gemm2(
    const float* __restrict__ s1, const float* __restrict__ s2,
    const unsigned short* __restrict__ hw, const float* __restrict__ h_b,
    float* __restrict__ outpre) {
  const int tid = threadIdx.x, lane = tid & 63, wid = tid >> 6;
  const int r0 = blockIdx.y * 16;
  const int c0 = blockIdx.x * 64 + wid * 16;
  f32x4 acc = (f32x4){0.f, 0.f, 0.f, 0.f};
  const int arow = r0 + (lane & 15);
  const float* s1p = s1 + (size_t)arow * D + (lane >> 4) * 8;
  const float* s2p = s2 + (size_t)arow * D + (lane >> 4) * 8;
  const unsigned short* bRow = hw + (size_t)(c0 + (lane & 15)) * D + (lane >> 4) * 8;
#pragma unroll
  for (int kt = 0; kt < D / 32; kt++) {
    float4 u0 = *(const float4*)(s1p + kt * 32);
    float4 u1 = *(const float4*)(s1p + kt * 32 + 4);
    float4 w0 = *(const float4*)(s2p + kt * 32);
    float4 w1 = *(const float4*)(s2p + kt * 32 + 4);
    int4 yi;
    yi.x = cvtpk(w0.x * frcp(u0.x + 1e-6f), w0.y * frcp(u0.y + 1e-6f));
    yi.y = cvtpk(w0.z * frcp(u0.z + 1e-6f), w0.w * frcp(u0.w + 1e-6f));
    yi.z = cvtpk(w1.x * frcp(u1.x + 1e-6f), w1.y * frcp(u1.y + 1e-6f));
    yi.w = cvtpk(w1.z * frcp(u1.z + 1e-6f), w1.w * frcp(u1.w + 1e-6f));
    bf16x8 af = *(bf16x8*)&yi;
    bf16x8 bf_ = *(const bf16x8*)(bRow + kt * 32);
    acc = __builtin_amdgcn_mfma_f32_16x16x32_bf16(af, bf_, acc, 0, 0, 0);
  }
  const int col = c0 + (lane & 15);
  const float hb = h_b[col];
#pragma unroll
  for (int r = 0; r < 4; r++) {
    const int row = r0 + (lane >> 4) * 4 + r;
    outpre[(size_t)row * D + col] = acc[r] + hb;
  }
}

// ---------------- gather rows ----------------
__global__ void k_gather(const float* __restrict__ outpre, const int* __restrict__ ii,
                         float* __restrict__ out) {
  const long total4 = (long)RTOT * (D / 4); // 96 float4 per row
  for (long i = blockIdx.x * (long)blockDim.x + threadIdx.x; i < total4;
       i += (long)gridDim.x * blockDim.x) {
    const long row = i / (D / 4);
    const int q = (int)(i % (D / 4));
    const int b = (int)(row >> 14);
    const int n = (int)(row & (NROWS - 1));
    const int g = ii[n];
    ((float4*)out)[i] = ((const float4*)outpre)[((size_t)(b * MG + g)) * (D / 4) + q];
  }
}

extern "C" void kernel_launch(void* const* d_in, const int* in_sizes, int n_in,
                              void* d_out, int out_size, void* d_ws, size_t ws_size,
                              hipStream_t stream) {
  const float* x = (const float*)d_in[0];
  const int* ii = (const int*)d_in[1];
  const float* f_w = (const float*)d_in[2];
  const float* f_b = (const float*)d_in[3];
  const float* g_w = (const float*)d_in[4];
  const float* g_b = (const float*)d_in[5];
  const float* h_w = (const float*)d_in[6];
  const float* h_b = (const float*)d_in[7];
  float* out = (float*)d_out;

  char* ws = (char*)d_ws;
  size_t off = 0;
  auto alloc = [&](size_t bytes) {
    size_t p = off;
    off = (off + bytes + 255) & ~(size_t)255;
    return p;
  };
  unsigned short* wt2 = (unsigned short*)(ws + alloc((size_t)NC * D * 2));
  unsigned short* hw = (unsigned short*)(ws + alloc((size_t)D * D * 2));
  float* s1acc = (float*)(ws + alloc((size_t)BATCH * MG * D * 4)); // 3 MB
  float* s2acc = (float*)(ws + alloc((size_t)BATCH * MG * D * 4)); // contiguous after s1acc
  float* outpre = (float*)(ws + alloc((size_t)BATCH * MG * D * 4));
  int* csr_start = (int*)(ws + alloc((MG + 1) * 4));
  int* csr_rows = (int*)(ws + alloc((size_t)NROWS * 4));
  int* grp_sorted = (int*)(ws + alloc((size_t)NROWS * 4));

  hipMemsetAsync(s1acc, 0, (size_t)2 * BATCH * MG * D * 4, stream); // s1acc+s2acc

  k_build_w<<<dim3(1152), dim3(256), 0, stream>>>(g_w, f_w, h_w, wt2, hw);
  k_csr<<<dim3(1), dim3(MG), 0, stream>>>(ii, csr_start, csr_rows, grp_sorted);
  k_gemm1<<<dim3(NJB * NMT), dim3(256), 0, stream>>>(x, wt2, g_b, f_b, csr_rows,
                                                     grp_sorted, s1acc, s2acc);
  k_gemm2<<<dim3(D / 64, (BATCH * MG) / 16), dim3(256), 0, stream>>>(s1acc, s2acc, hw, h_b,
                                                                     outpre);
  k_gather<<<dim3(4096), dim3(256), 0, stream>>>(outpre, ii, out);
}